// Round 14
// baseline (125.579 us; speedup 1.0000x reference)
//
#include <hip/hip_runtime.h>
#include <math.h>

#define HW 16384
#define WD 128
#define HD 128
#define CIN 64
#define CH 128
#define EPSV 1e-5f

typedef __attribute__((ext_vector_type(8))) short short8;
typedef __attribute__((ext_vector_type(4))) short short4v;
typedef __attribute__((ext_vector_type(4))) float f32x4;

__device__ __forceinline__ short f2bf(float x) {
  unsigned u = __float_as_uint(x);
  u += 0x7FFFu + ((u >> 16) & 1u);   // RNE
  return (short)(u >> 16);
}
__device__ __forceinline__ float bf2f(short x) {
  return __uint_as_float(((unsigned)(unsigned short)x) << 16);
}

// ---------------------------------------------------------------------------
// Single fused prep. df2 branch = v8 PERMUTED layout (pairs with k_filt_v10):
//   mslot 0..15:  g=ms>>2, r=ms&3 -> tap g*5+r
//   mslot 16..31: g0 -> 20+r (row4); g1 -> r*5+4 (col4, via fwT);
//                 g2 -> 24 iff r==0; else zero row.   k8s = k8 ^ (ms&7).
// ---------------------------------------------------------------------------
__global__ __launch_bounds__(256) void k_prep_all(
    const float* __restrict__ cw, const float* __restrict__ w3,
    const float* __restrict__ spw, const float* __restrict__ outw,
    const float* __restrict__ rgb, const float* __restrict__ ev,
    const float* __restrict__ df2,
    short* __restrict__ cwp, short* __restrict__ w3p,
    short* __restrict__ spwp, short* __restrict__ outwp,
    short* __restrict__ xT_rgb, short* __restrict__ xT_ev,
    short* __restrict__ df2p) {
  int idx = blockIdx.x * 256 + threadIdx.x;
  if (idx < 8192) {            // cwp: q2 x m128 x grp4 x j8
    int j = idx & 7, grp = (idx >> 3) & 3, m = (idx >> 5) & 127, q = idx >> 12;
    cwp[idx] = f2bf(cw[m * CIN + q * 32 + grp * 8 + j]);
  } else if (idx < 155648) {   // w3p: ks36 x m128 x grp4 x j8
    int i = idx - 8192;
    int j = i & 7, grp = (i >> 3) & 3, m = (i >> 5) & 127, ks = i >> 12;
    int tap = ks >> 2, q = ks & 3;
    int c = q * 32 + grp * 8 + j;
    w3p[i] = f2bf(w3[(m * CH + c) * 9 + tap]);
  } else if (idx < 172032) {   // spwp: q4 x m128 x grp4 x j8
    int i = idx - 155648;
    int j = i & 7, grp = (i >> 3) & 3, m = (i >> 5) & 127, q = i >> 12;
    spwp[i] = f2bf(spw[m * CH + q * 32 + grp * 8 + j]);
  } else if (idx < 180224) {   // outwp: q4 x m64 x grp4 x j8
    int i = idx - 172032;
    int j = i & 7, grp = (i >> 3) & 3, m = (i >> 5) & 63, q = i >> 11;
    outwp[i] = f2bf(outw[m * CH + q * 32 + grp * 8 + j]);
  } else if (idx < 212992) {   // xT: one pixel task = 8 short8 stores
    int i = idx - 180224;      // [0, 32768)
    int img = i >> 14, p = i & 16383;
    const float* x = img ? ev : rgb;
    short* xT = img ? xT_ev : xT_rgb;
#pragma unroll
    for (int cb = 0; cb < 8; ++cb) {
      short8 v;
#pragma unroll
      for (int j = 0; j < 8; ++j) v[j] = f2bf(x[(cb * 8 + j) * HW + p]);
      *(short8*)(xT + p * CIN + cb * 8) = v;
    }
  } else {                     // df2p: v8 permuted [c][ms32][k8s16][8]
    int i = idx - 212992;      // [0, 524288)
    int j = i & 7;
    int slotp = (i >> 3) & 511;
    int c = i >> 12;
    int ms = slotp >> 4, k8l = slotp & 15;
    int k8 = k8l ^ (ms & 7);
    int k = k8 * 8 + j;
    int t;
    if (ms < 16) {
      t = (ms >> 2) * 5 + (ms & 3);
    } else {
      int g = (ms >> 2) & 3, r = ms & 3;
      if (g == 0) t = 20 + r;
      else if (g == 1) t = r * 5 + 4;
      else if (g == 2 && r == 0) t = 24;
      else t = -1;
    }
    float v = (t >= 0) ? df2[(c * 25 + t) * CH + k] : 0.f;
    df2p[i] = f2bf(v);
  }
}

// ---------------------------------------------------------------------------
// Kernel 1 (MFMA): featT = bf16(LN_c(conv1x1(x, cw)))  [p][128]
// ---------------------------------------------------------------------------
__global__ __launch_bounds__(256) void k_feat_mfma(
    const short* __restrict__ xT_rgb, const short* __restrict__ xT_ev,
    const short* __restrict__ cwp, const float* __restrict__ g,
    const float* __restrict__ b,
    short* __restrict__ featT_rgb, short* __restrict__ featT_ev) {
  __shared__ float sg[CH], sb[CH];
  int tid = threadIdx.x;
  if (tid < CH) { sg[tid] = g[tid]; sb[tid] = b[tid]; }
  __syncthreads();
  const short* xT = blockIdx.z ? xT_ev : xT_rgb;
  short* featT = blockIdx.z ? featT_ev : featT_rgb;
  int wave = tid >> 6, lane = tid & 63, col = lane & 15, grp = lane >> 4;
  int p = blockIdx.x * 64 + wave * 16 + col;

  const short8* bp = (const short8*)(xT + p * CIN);
  short8 bq0 = bp[grp], bq1 = bp[4 + grp];
  const short8* ap = (const short8*)cwp;

  f32x4 acc[8];
#pragma unroll
  for (int mt = 0; mt < 8; ++mt) {
    acc[mt] = (f32x4){0.f, 0.f, 0.f, 0.f};
    short8 a0 = ap[(0 * 128 + mt * 16 + col) * 4 + grp];
    short8 a1 = ap[(1 * 128 + mt * 16 + col) * 4 + grp];
    acc[mt] = __builtin_amdgcn_mfma_f32_16x16x32_bf16(a0, bq0, acc[mt], 0, 0, 0);
    acc[mt] = __builtin_amdgcn_mfma_f32_16x16x32_bf16(a1, bq1, acc[mt], 0, 0, 0);
  }
  float s = 0.f, s2 = 0.f;
#pragma unroll
  for (int mt = 0; mt < 8; ++mt)
#pragma unroll
    for (int r = 0; r < 4; ++r) { float v = acc[mt][r]; s += v; s2 += v * v; }
  s += __shfl_xor(s, 16);  s += __shfl_xor(s, 32);
  s2 += __shfl_xor(s2, 16); s2 += __shfl_xor(s2, 32);
  float mean = s * (1.f / CH);
  float var = s2 * (1.f / CH) - mean * mean;
  float rinv = rsqrtf(var + EPSV);
#pragma unroll
  for (int mt = 0; mt < 8; ++mt) {
    short4v fv;
#pragma unroll
    for (int r = 0; r < 4; ++r) {
      int m = mt * 16 + grp * 4 + r;
      fv[r] = f2bf((acc[mt][r] - mean) * rinv * sg[m] + sb[m]);
    }
    *(short4v*)(featT + p * CH + mt * 16 + grp * 4) = fv;
  }
}

// ---------------------------------------------------------------------------
// Kernel 2 v3 (MFMA, VERIFIED BEST of 4 variants): rT = bf16(relu(conv3x3)).
// FROZEN: v4 (LDS staging) and v5 (m-quarter) both regressed.
// ---------------------------------------------------------------------------
__global__ __launch_bounds__(256) void k_conv3_v3(
    const short* __restrict__ featT_rgb, const short* __restrict__ featT_ev,
    const short* __restrict__ w3p,
    short* __restrict__ rT_rgb, short* __restrict__ rT_ev) {
  const short* featT = blockIdx.z ? featT_ev : featT_rgb;
  short* rT = blockIdx.z ? rT_ev : rT_rgb;
  int tid = threadIdx.x, wave = tid >> 6, lane = tid & 63;
  int col = lane & 15, grp = lane >> 4;
  int mh = wave & 1;                       // m-half
  int ty = (blockIdx.x >> 3) * 4 + (wave >> 1) * 2;
  int tx = (blockIdx.x & 7) * 16;
  int x = tx + col;

  f32x4 acc[2][4];
#pragma unroll
  for (int s = 0; s < 2; ++s)
#pragma unroll
    for (int mt = 0; mt < 4; ++mt) acc[s][mt] = (f32x4){0.f, 0.f, 0.f, 0.f};

  const short8* ap = (const short8*)w3p;
#pragma unroll
  for (int ks = 0; ks < 36; ++ks) {
    const int tap = ks >> 2, q = ks & 3;
    const int dy = tap / 3 - 1, dx = tap % 3 - 1;
    int xs = x + dx;
    bool xok = (unsigned)xs < (unsigned)WD;
    int y0 = ty + dy, y1 = ty + 1 + dy;
    short8 b0 = {0, 0, 0, 0, 0, 0, 0, 0}, b1 = {0, 0, 0, 0, 0, 0, 0, 0};
    if (xok && (unsigned)y0 < (unsigned)HD)
      b0 = *(const short8*)(featT + (y0 * WD + xs) * CH + q * 32 + grp * 8);
    if (xok && (unsigned)y1 < (unsigned)HD)
      b1 = *(const short8*)(featT + (y1 * WD + xs) * CH + q * 32 + grp * 8);
#pragma unroll
    for (int mt = 0; mt < 4; ++mt) {
      short8 a = ap[(ks * 128 + (mh * 4 + mt) * 16 + col) * 4 + grp];
      acc[0][mt] = __builtin_amdgcn_mfma_f32_16x16x32_bf16(a, b0, acc[0][mt], 0, 0, 0);
      acc[1][mt] = __builtin_amdgcn_mfma_f32_16x16x32_bf16(a, b1, acc[1][mt], 0, 0, 0);
    }
  }
#pragma unroll
  for (int s = 0; s < 2; ++s) {
    int p = (ty + s) * WD + x;
#pragma unroll
    for (int mt = 0; mt < 4; ++mt) {
      short4v v;
#pragma unroll
      for (int r = 0; r < 4; ++r) v[r] = f2bf(fmaxf(acc[s][mt][r], 0.f));
      *(short4v*)(rT + p * CH + (mh * 4 + mt) * 16 + grp * 4) = v;
    }
  }
}

// ---------------------------------------------------------------------------
// Kernel 3 v10: v8's merged ds_read2 epilogue at launch_bounds(256,2) —
// the register cap (512/2=256 vs 170 at 3 waves) removes the spill cause.
// Spill tell: WRITE_SIZE >> 8 MB means revert to v6.
// ---------------------------------------------------------------------------
__global__ __launch_bounds__(256, 2) void k_filt_v10(
    const short* __restrict__ featT_rgb, const short* __restrict__ featT_ev,
    const short* __restrict__ rT_rgb, const short* __restrict__ rT_ev,
    const short* __restrict__ df2p,
    short* __restrict__ enT_rgb, short* __restrict__ enT_ev) {
  __shared__ short lsA[4 * 512 * 8];     // 32 KB
  __shared__ float fwall[2 * 4 * 408];   // 13.1 KB: [copy][c][408]
  const short* featT = blockIdx.z ? featT_ev : featT_rgb;
  const short* rT = blockIdx.z ? rT_ev : rT_rgb;
  short* enT = blockIdx.z ? enT_ev : enT_rgb;
  int tid = threadIdx.x;
  int wave = tid >> 6, lane = tid & 63;
  int col = lane & 15, grp = lane >> 4;
  int ty0 = (blockIdx.x >> 3) * 16, tx0 = (blockIdx.x & 7) * 16;
  int c0 = blockIdx.y * 4;
  int py0 = ty0 + wave * 4;
  int pxx = tx0 + col;

  // stage df2p chunk (linear copy; swizzle pre-baked in source)
  {
    const short8* gsrc = (const short8*)(df2p + (size_t)c0 * 4096);
    short8* lA = (short8*)lsA;
    for (int i = tid; i < 2048; i += 256) lA[i] = gsrc[i];
  }
  // stage feat window fw + transposed fwT (rows/cols ty0-2.., tx0-2..)
  for (int px = tid; px < 400; px += 256) {
    int wr = px / 20, wc = px % 20;
    int y = ty0 + wr - 2, x = tx0 + wc - 2;
    short4v v = {0, 0, 0, 0};
    if ((unsigned)y < (unsigned)HD && (unsigned)x < (unsigned)WD)
      v = *(const short4v*)(featT + (y * WD + x) * CH + c0);
#pragma unroll
    for (int ci = 0; ci < 4; ++ci) {
      float f = bf2f(v[ci]);
      fwall[ci * 408 + wr * 20 + wc] = f;
      fwall[1632 + ci * 408 + wc * 20 + wr] = f;
    }
  }
  if (tid < 64) {   // zero tails
    int copy = tid >> 5, cc = (tid >> 3) & 3, k = tid & 7;
    fwall[copy * 1632 + cc * 408 + 400 + k] = 0.f;
  }

  // B fragments, resident for whole c-loop (pinned)
  short8 rv[4][4];
#pragma unroll
  for (int s = 0; s < 4; ++s) {
    const short8* bp = (const short8*)(rT + ((py0 + s) * WD + pxx) * CH);
#pragma unroll
    for (int q = 0; q < 4; ++q) rv[s][q] = bp[q * 4 + grp];
  }
#pragma unroll
  for (int s = 0; s < 4; ++s)
#pragma unroll
    for (int q = 0; q < 4; ++q) asm volatile("" :: "v"(rv[s][q]));

  // epilogue bases: every lane's 4 taps are base+{0,1,2,3}
  int rowb = wave * 4;
  int base0 = (rowb + grp) * 20 + col;                      // mtile0
  int step1 = (grp == 1) ? 1 : 20;
  int base1;
  if (grp == 0)      base1 = (rowb + 4) * 20 + col;         // row4
  else if (grp == 1) base1 = 1632 + (col + 4) * 20 + rowb;  // col4 via fwT
  else if (grp == 2) base1 = (rowb + 4) * 20 + col + 4;     // (4,4)+strays*0
  else               base1 = rowb * 20 + col;               // dummy *0
  __syncthreads();

  const short8* lA8 = (const short8*)lsA;
  short* stp = enT + ((py0 + grp) * WD + pxx) * CH + c0;
  short4v sv;

#pragma unroll
  for (int c = 0; c < 4; ++c) {
    int base0c = c * 512 + col * 16;
    int base1c = base0c + 256;
    short8 a[4];
    f32x4 acc0[4], acc1[4];
    // m-tile 0 (tap-slots 0..15)
#pragma unroll
    for (int q = 0; q < 4; ++q) a[q] = lA8[base0c + (((q << 2) | grp) ^ (col & 7))];
#pragma unroll
    for (int s = 0; s < 4; ++s) {
      acc0[s] = (f32x4){0.f, 0.f, 0.f, 0.f};
#pragma unroll
      for (int q = 0; q < 4; ++q)
        acc0[s] = __builtin_amdgcn_mfma_f32_16x16x32_bf16(a[q], rv[s][q], acc0[s], 0, 0, 0);
    }
    // m-tile 1 (tap-slots 16..31)
#pragma unroll
    for (int q = 0; q < 4; ++q) a[q] = lA8[base1c + (((q << 2) | grp) ^ (col & 7))];
#pragma unroll
    for (int s = 0; s < 4; ++s) {
      acc1[s] = (f32x4){0.f, 0.f, 0.f, 0.f};
#pragma unroll
      for (int q = 0; q < 4; ++q)
        acc1[s] = __builtin_amdgcn_mfma_f32_16x16x32_bf16(a[q], rv[s][q], acc1[s], 0, 0, 0);
    }
    // batched epilogue: const-offset quads (ds_read2-able)
    int cb = c * 408;
    float part[4];
#pragma unroll
    for (int s = 0; s < 4; ++s) {
      int i0 = cb + base0 + s * 20;
      int i1 = cb + base1 + s * step1;
      float p = fwall[i0] * acc0[s][0] + fwall[i0 + 1] * acc0[s][1]
              + fwall[i0 + 2] * acc0[s][2] + fwall[i0 + 3] * acc0[s][3]
              + fwall[i1] * acc1[s][0] + fwall[i1 + 1] * acc1[s][1]
              + fwall[i1 + 2] * acc1[s][2] + fwall[i1 + 3] * acc1[s][3];
      part[s] = p;
    }
#pragma unroll
    for (int s = 0; s < 4; ++s) part[s] += __shfl_xor(part[s], 16);
#pragma unroll
    for (int s = 0; s < 4; ++s) part[s] += __shfl_xor(part[s], 32);
    float val = (grp == 0) ? part[0] : (grp == 1) ? part[1]
              : (grp == 2) ? part[2] : part[3];
    sv[c] = f2bf(val);
  }
  *(short4v*)stp = sv;
}

// ---------------------------------------------------------------------------
// Kernel 4 v2: fuse+LN+out with paired-wave m-split (2 waves share 16 px;
// each wave does half the o-channels). 512 blocks -> 2 waves/SIMD (2x TLP).
// ---------------------------------------------------------------------------
__global__ __launch_bounds__(256) void k_post_v2(
    const short* __restrict__ enT_rgb, const short* __restrict__ enT_ev,
    const short* __restrict__ featT_rgb,
    const short* __restrict__ spwp, const short* __restrict__ outwp,
    const float* __restrict__ g, const float* __restrict__ b,
    float* __restrict__ out) {
  __shared__ short nlds[2][16 * 136];    // 8.7 KB: per-pair 16px x 128o
  __shared__ float sst[2][2][16][2];     // [pair][half][px][s,s2]
  __shared__ float sg[CH], sb[CH];
  int tid = threadIdx.x;
  if (tid < CH) { sg[tid] = g[tid]; sb[tid] = b[tid]; }
  __syncthreads();
  int wave = tid >> 6, lane = tid & 63, col = lane & 15, grp = lane >> 4;
  int pr = wave >> 1, h = wave & 1;
  int p = blockIdx.x * 32 + pr * 16 + col;

  // gate GEMM half: mt' = h*4 + mt (o-range h*64 .. h*64+63)
  const short8* bp = (const short8*)(enT_ev + p * CH);
  short8 bq[4];
#pragma unroll
  for (int q = 0; q < 4; ++q) bq[q] = bp[q * 4 + grp];
  const short8* ap = (const short8*)spwp;
  f32x4 z[4];
#pragma unroll
  for (int mt = 0; mt < 4; ++mt) {
    int mtp = h * 4 + mt;
    z[mt] = (f32x4){0.f, 0.f, 0.f, 0.f};
#pragma unroll
    for (int q = 0; q < 4; ++q)
      z[mt] = __builtin_amdgcn_mfma_f32_16x16x32_bf16(
          ap[(q * 128 + mtp * 16 + col) * 4 + grp], bq[q], z[mt], 0, 0, 0);
  }

  // fused + partial LN stats (this half's 64 channels)
  const short4v* er = (const short4v*)(enT_rgb + p * CH);
  const short4v* fr = (const short4v*)(featT_rgb + p * CH);
  float fused[4][4];
  float s = 0.f, s2 = 0.f;
#pragma unroll
  for (int mt = 0; mt < 4; ++mt) {
    int mtp = h * 4 + mt;
    short4v e4 = er[mtp * 4 + grp];
    short4v f4 = fr[mtp * 4 + grp];
#pragma unroll
    for (int r = 0; r < 4; ++r) {
      float sig = 1.f / (1.f + __expf(-z[mt][r]));
      float f = bf2f(e4[r]) * (1.f + sig) + bf2f(f4[r]);
      fused[mt][r] = f; s += f; s2 += f * f;
    }
  }
  s += __shfl_xor(s, 16);  s += __shfl_xor(s, 32);
  s2 += __shfl_xor(s2, 16); s2 += __shfl_xor(s2, 32);
  if (grp == 0) { sst[pr][h][col][0] = s; sst[pr][h][col][1] = s2; }
  __syncthreads();
  float st  = sst[pr][0][col][0] + sst[pr][1][col][0];
  float st2 = sst[pr][0][col][1] + sst[pr][1][col][1];
  float mean = st * (1.f / CH);
  float var = st2 * (1.f / CH) - mean * mean;
  float rinv = rsqrtf(var + EPSV);

  // normalize -> bf16 -> pair LDS (this half's 64 o)
  short* nl = &nlds[pr][0];
#pragma unroll
  for (int mt = 0; mt < 4; ++mt) {
    int mtp = h * 4 + mt;
    short4v nv;
#pragma unroll
    for (int r = 0; r < 4; ++r) {
      int o = mtp * 16 + grp * 4 + r;
      nv[r] = f2bf((fused[mt][r] - mean) * rinv * sg[o] + sb[o]);
    }
    *(short4v*)(nl + col * 136 + mtp * 16 + grp * 4) = nv;
  }
  __syncthreads();

  // out GEMM: 64 o split across the pair (2 mt each)
  short8 nb[4];
#pragma unroll
  for (int q = 0; q < 4; ++q)
    nb[q] = *(const short8*)(nl + col * 136 + q * 32 + grp * 8);
  const short8* op = (const short8*)outwp;
#pragma unroll
  for (int mt2 = 0; mt2 < 2; ++mt2) {
    int mo = h * 2 + mt2;
    f32x4 oacc = {0.f, 0.f, 0.f, 0.f};
#pragma unroll
    for (int q = 0; q < 4; ++q)
      oacc = __builtin_amdgcn_mfma_f32_16x16x32_bf16(
          op[(q * 64 + mo * 16 + col) * 4 + grp], nb[q], oacc, 0, 0, 0);
#pragma unroll
    for (int r = 0; r < 4; ++r)
      out[(mo * 16 + grp * 4 + r) * HW + p] = oacc[r];
  }
}

extern "C" void kernel_launch(void* const* d_in, const int* in_sizes, int n_in,
                              void* d_out, int out_size, void* d_ws, size_t ws_size,
                              hipStream_t stream) {
  const float* rgb  = (const float*)d_in[0];
  const float* ev   = (const float*)d_in[1];
  const float* cw   = (const float*)d_in[2];
  const float* g    = (const float*)d_in[3];
  const float* b    = (const float*)d_in[4];
  const float* w3   = (const float*)d_in[5];
  const float* df2  = (const float*)d_in[6];
  const float* spw  = (const float*)d_in[7];
  const float* outw = (const float*)d_in[8];
  float* out = (float*)d_out;
  char* wsb = (char*)d_ws;

  const size_t MB = 1u << 20;
  short* featT_rgb = (short*)(wsb);             // 4 MB
  short* featT_ev  = (short*)(wsb + 4 * MB);    // 4 MB
  short* rT_rgb    = (short*)(wsb + 8 * MB);    // 4 MB
  short* rT_ev     = (short*)(wsb + 12 * MB);   // 4 MB
  short* enT_rgb   = (short*)(wsb + 16 * MB);   // 4 MB
  short* enT_ev    = (short*)(wsb + 20 * MB);   // 4 MB
  short* xT_rgb    = (short*)(wsb + 24 * MB);   // 2 MB
  short* xT_ev     = (short*)(wsb + 26 * MB);   // 2 MB
  short* df2p      = (short*)(wsb + 28 * MB);   // 1 MB
  short* w3p       = (short*)(wsb + 29 * MB);   // 288 KB
  short* cwp       = (short*)(wsb + 30 * MB);   // 16 KB
  short* spwp      = (short*)(wsb + 31 * MB);   // 32 KB
  short* outwp     = (short*)(wsb + 32 * MB);   // 16 KB

  hipLaunchKernelGGL(k_prep_all, dim3(2880), dim3(256), 0, stream,
                     cw, w3, spw, outw, rgb, ev, df2,
                     cwp, w3p, spwp, outwp, xT_rgb, xT_ev, df2p);
  hipLaunchKernelGGL(k_feat_mfma, dim3(256, 1, 2), dim3(256), 0, stream,
                     xT_rgb, xT_ev, cwp, g, b, featT_rgb, featT_ev);
  hipLaunchKernelGGL(k_conv3_v3, dim3(256, 1, 2), dim3(256), 0, stream,
                     featT_rgb, featT_ev, w3p, rT_rgb, rT_ev);
  hipLaunchKernelGGL(k_filt_v10, dim3(64, 32, 2), dim3(256), 0, stream,
                     featT_rgb, featT_ev, rT_rgb, rT_ev, df2p, enT_rgb, enT_ev);
  hipLaunchKernelGGL(k_post_v2, dim3(512), dim3(256), 0, stream,
                     enT_rgb, enT_ev, featT_rgb, spwp, outwp, g, b, out);
}

// Round 15
// 113.178 us; speedup vs baseline: 1.1096x; 1.1096x over previous
//
#include <hip/hip_runtime.h>
#include <math.h>

#define HW 16384
#define WD 128
#define HD 128
#define CIN 64
#define CH 128
#define EPSV 1e-5f

typedef __attribute__((ext_vector_type(8))) short short8;
typedef __attribute__((ext_vector_type(4))) short short4v;
typedef __attribute__((ext_vector_type(4))) float f32x4;

__device__ __forceinline__ short f2bf(float x) {
  unsigned u = __float_as_uint(x);
  u += 0x7FFFu + ((u >> 16) & 1u);   // RNE
  return (short)(u >> 16);
}
__device__ __forceinline__ float bf2f(short x) {
  return __uint_as_float(((unsigned)(unsigned short)x) << 16);
}

// ---------------------------------------------------------------------------
// Single fused prep: cw / w3 / spw / outw / xT / df2p by index range.
// ---------------------------------------------------------------------------
__global__ __launch_bounds__(256) void k_prep_all(
    const float* __restrict__ cw, const float* __restrict__ w3,
    const float* __restrict__ spw, const float* __restrict__ outw,
    const float* __restrict__ rgb, const float* __restrict__ ev,
    const float* __restrict__ df2,
    short* __restrict__ cwp, short* __restrict__ w3p,
    short* __restrict__ spwp, short* __restrict__ outwp,
    short* __restrict__ xT_rgb, short* __restrict__ xT_ev,
    short* __restrict__ df2p) {
  int idx = blockIdx.x * 256 + threadIdx.x;
  if (idx < 8192) {            // cwp: q2 x m128 x grp4 x j8
    int j = idx & 7, grp = (idx >> 3) & 3, m = (idx >> 5) & 127, q = idx >> 12;
    cwp[idx] = f2bf(cw[m * CIN + q * 32 + grp * 8 + j]);
  } else if (idx < 155648) {   // w3p: ks36 x m128 x grp4 x j8
    int i = idx - 8192;
    int j = i & 7, grp = (i >> 3) & 3, m = (i >> 5) & 127, ks = i >> 12;
    int tap = ks >> 2, q = ks & 3;
    int c = q * 32 + grp * 8 + j;
    w3p[i] = f2bf(w3[(m * CH + c) * 9 + tap]);
  } else if (idx < 172032) {   // spwp: q4 x m128 x grp4 x j8
    int i = idx - 155648;
    int j = i & 7, grp = (i >> 3) & 3, m = (i >> 5) & 127, q = i >> 12;
    spwp[i] = f2bf(spw[m * CH + q * 32 + grp * 8 + j]);
  } else if (idx < 180224) {   // outwp: q4 x m64 x grp4 x j8
    int i = idx - 172032;
    int j = i & 7, grp = (i >> 3) & 3, m = (i >> 5) & 63, q = i >> 11;
    outwp[i] = f2bf(outw[m * CH + q * 32 + grp * 8 + j]);
  } else if (idx < 212992) {   // xT: one pixel task = 8 short8 stores
    int i = idx - 180224;      // [0, 32768)
    int img = i >> 14, p = i & 16383;
    const float* x = img ? ev : rgb;
    short* xT = img ? xT_ev : xT_rgb;
#pragma unroll
    for (int cb = 0; cb < 8; ++cb) {
      short8 v;
#pragma unroll
      for (int j = 0; j < 8; ++j) v[j] = f2bf(x[(cb * 8 + j) * HW + p]);
      *(short8*)(xT + p * CIN + cb * 8) = v;
    }
  } else {                     // df2p: [c][t*16 + (k8^(t&7))][8]  (v6 pair)
    int i = idx - 212992;      // [0, 524288)
    int j = i & 7;
    int slotp = (i >> 3) & 511;
    int c = i >> 12;
    int t = slotp >> 4, k8l = slotp & 15;
    int k8 = k8l ^ (t & 7);
    float v = (t < 25) ? df2[(c * 25 + t) * CH + k8 * 8 + j] : 0.f;
    df2p[i] = f2bf(v);
  }
}

// ---------------------------------------------------------------------------
// Kernel 1 (MFMA): featT = bf16(LN_c(conv1x1(x, cw)))  [p][128]
// ---------------------------------------------------------------------------
__global__ __launch_bounds__(256) void k_feat_mfma(
    const short* __restrict__ xT_rgb, const short* __restrict__ xT_ev,
    const short* __restrict__ cwp, const float* __restrict__ g,
    const float* __restrict__ b,
    short* __restrict__ featT_rgb, short* __restrict__ featT_ev) {
  __shared__ float sg[CH], sb[CH];
  int tid = threadIdx.x;
  if (tid < CH) { sg[tid] = g[tid]; sb[tid] = b[tid]; }
  __syncthreads();
  const short* xT = blockIdx.z ? xT_ev : xT_rgb;
  short* featT = blockIdx.z ? featT_ev : featT_rgb;
  int wave = tid >> 6, lane = tid & 63, col = lane & 15, grp = lane >> 4;
  int p = blockIdx.x * 64 + wave * 16 + col;

  const short8* bp = (const short8*)(xT + p * CIN);
  short8 bq0 = bp[grp], bq1 = bp[4 + grp];
  const short8* ap = (const short8*)cwp;

  f32x4 acc[8];
#pragma unroll
  for (int mt = 0; mt < 8; ++mt) {
    acc[mt] = (f32x4){0.f, 0.f, 0.f, 0.f};
    short8 a0 = ap[(0 * 128 + mt * 16 + col) * 4 + grp];
    short8 a1 = ap[(1 * 128 + mt * 16 + col) * 4 + grp];
    acc[mt] = __builtin_amdgcn_mfma_f32_16x16x32_bf16(a0, bq0, acc[mt], 0, 0, 0);
    acc[mt] = __builtin_amdgcn_mfma_f32_16x16x32_bf16(a1, bq1, acc[mt], 0, 0, 0);
  }
  float s = 0.f, s2 = 0.f;
#pragma unroll
  for (int mt = 0; mt < 8; ++mt)
#pragma unroll
    for (int r = 0; r < 4; ++r) { float v = acc[mt][r]; s += v; s2 += v * v; }
  s += __shfl_xor(s, 16);  s += __shfl_xor(s, 32);
  s2 += __shfl_xor(s2, 16); s2 += __shfl_xor(s2, 32);
  float mean = s * (1.f / CH);
  float var = s2 * (1.f / CH) - mean * mean;
  float rinv = rsqrtf(var + EPSV);
#pragma unroll
  for (int mt = 0; mt < 8; ++mt) {
    short4v fv;
#pragma unroll
    for (int r = 0; r < 4; ++r) {
      int m = mt * 16 + grp * 4 + r;
      fv[r] = f2bf((acc[mt][r] - mean) * rinv * sg[m] + sb[m]);
    }
    *(short4v*)(featT + p * CH + mt * 16 + grp * 4) = fv;
  }
}

// ---------------------------------------------------------------------------
// Kernel 2 v3 (MFMA, VERIFIED BEST of 4 variants): rT = bf16(relu(conv3x3)),
// implicit im2col, streaming global loads, m-half split, ks fully unrolled.
// FROZEN: v4 (LDS staging) and v5 (m-quarter) both regressed.
// ---------------------------------------------------------------------------
__global__ __launch_bounds__(256) void k_conv3_v3(
    const short* __restrict__ featT_rgb, const short* __restrict__ featT_ev,
    const short* __restrict__ w3p,
    short* __restrict__ rT_rgb, short* __restrict__ rT_ev) {
  const short* featT = blockIdx.z ? featT_ev : featT_rgb;
  short* rT = blockIdx.z ? rT_ev : rT_rgb;
  int tid = threadIdx.x, wave = tid >> 6, lane = tid & 63;
  int col = lane & 15, grp = lane >> 4;
  int mh = wave & 1;                       // m-half
  int ty = (blockIdx.x >> 3) * 4 + (wave >> 1) * 2;
  int tx = (blockIdx.x & 7) * 16;
  int x = tx + col;

  f32x4 acc[2][4];
#pragma unroll
  for (int s = 0; s < 2; ++s)
#pragma unroll
    for (int mt = 0; mt < 4; ++mt) acc[s][mt] = (f32x4){0.f, 0.f, 0.f, 0.f};

  const short8* ap = (const short8*)w3p;
#pragma unroll
  for (int ks = 0; ks < 36; ++ks) {
    const int tap = ks >> 2, q = ks & 3;
    const int dy = tap / 3 - 1, dx = tap % 3 - 1;
    int xs = x + dx;
    bool xok = (unsigned)xs < (unsigned)WD;
    int y0 = ty + dy, y1 = ty + 1 + dy;
    short8 b0 = {0, 0, 0, 0, 0, 0, 0, 0}, b1 = {0, 0, 0, 0, 0, 0, 0, 0};
    if (xok && (unsigned)y0 < (unsigned)HD)
      b0 = *(const short8*)(featT + (y0 * WD + xs) * CH + q * 32 + grp * 8);
    if (xok && (unsigned)y1 < (unsigned)HD)
      b1 = *(const short8*)(featT + (y1 * WD + xs) * CH + q * 32 + grp * 8);
#pragma unroll
    for (int mt = 0; mt < 4; ++mt) {
      short8 a = ap[(ks * 128 + (mh * 4 + mt) * 16 + col) * 4 + grp];
      acc[0][mt] = __builtin_amdgcn_mfma_f32_16x16x32_bf16(a, b0, acc[0][mt], 0, 0, 0);
      acc[1][mt] = __builtin_amdgcn_mfma_f32_16x16x32_bf16(a, b1, acc[1][mt], 0, 0, 0);
    }
  }
#pragma unroll
  for (int s = 0; s < 2; ++s) {
    int p = (ty + s) * WD + x;
#pragma unroll
    for (int mt = 0; mt < 4; ++mt) {
      short4v v;
#pragma unroll
      for (int r = 0; r < 4; ++r) v[r] = f2bf(fmaxf(acc[s][mt][r], 0.f));
      *(short4v*)(rT + p * CH + (mh * 4 + mt) * 16 + grp * 4) = v;
    }
  }
}

// ---------------------------------------------------------------------------
// Kernel 3 v6 (verified 59 us, EXACT R9/R13 config): fused filter gen + apply.
// FROZEN after 7 failed perturbations (v5 ILP, v7/v8 spills, c-chunk 8,
// v9 512-thread, v10 (256,2) occupancy loss).
// ---------------------------------------------------------------------------
__global__ __launch_bounds__(256, 3) void k_filt_v6(
    const short* __restrict__ featT_rgb, const short* __restrict__ featT_ev,
    const short* __restrict__ rT_rgb, const short* __restrict__ rT_ev,
    const short* __restrict__ df2p,
    short* __restrict__ enT_rgb, short* __restrict__ enT_ev) {
  __shared__ short lsA[4 * 512 * 8];     // 32 KB: 4 c x 512 slots x 16B
  __shared__ float fwv[4 * 400 + 64];    // 6.6 KB feat window + finite tail
  const short* featT = blockIdx.z ? featT_ev : featT_rgb;
  const short* rT = blockIdx.z ? rT_ev : rT_rgb;
  short* enT = blockIdx.z ? enT_ev : enT_rgb;
  int tid = threadIdx.x;
  int wave = tid >> 6, lane = tid & 63;
  int col = lane & 15, grp = lane >> 4;
  int ty0 = (blockIdx.x >> 3) * 16, tx0 = (blockIdx.x & 7) * 16;
  int c0 = blockIdx.y * 4;
  int py0 = ty0 + wave * 4;
  int pxx = tx0 + col;

  // stage df2p chunk (linear copy; swizzle pre-baked in source)
  {
    const short8* gsrc = (const short8*)(df2p + (size_t)c0 * 4096);
    short8* lA = (short8*)lsA;
    for (int i = tid; i < 2048; i += 256) lA[i] = gsrc[i];
  }
  // stage zero-padded feat window rows ty0-2..ty0+17, cols tx0-2..tx0+17
  for (int px = tid; px < 400; px += 256) {
    int wr = px / 20, wc = px % 20;
    int y = ty0 + wr - 2, x = tx0 + wc - 2;
    short4v v = {0, 0, 0, 0};
    if ((unsigned)y < (unsigned)HD && (unsigned)x < (unsigned)WD)
      v = *(const short4v*)(featT + (y * WD + x) * CH + c0);
#pragma unroll
    for (int ci = 0; ci < 4; ++ci) fwv[ci * 400 + px] = bf2f(v[ci]);
  }
  if (tid < 64) fwv[4 * 400 + tid] = 0.f;   // finite tail for tap>=25 reads

  // B fragments, resident for whole c-loop (pinned)
  short8 rv[4][4];
#pragma unroll
  for (int s = 0; s < 4; ++s) {
    const short8* bp = (const short8*)(rT + ((py0 + s) * WD + pxx) * CH);
#pragma unroll
    for (int q = 0; q < 4; ++q) rv[s][q] = bp[q * 4 + grp];
  }
#pragma unroll
  for (int s = 0; s < 4; ++s)
#pragma unroll
    for (int q = 0; q < 4; ++q) asm volatile("" :: "v"(rv[s][q]));

  // epilogue LDS indices (add s*20 at use)
  int idx0[4], idx1[4];
#pragma unroll
  for (int r = 0; r < 4; ++r) {
    int tap0 = grp * 4 + r;
    int tap1 = 16 + grp * 4 + r;
    idx0[r] = (wave * 4 + tap0 / 5) * 20 + col + tap0 % 5;
    idx1[r] = (wave * 4 + tap1 / 5) * 20 + col + tap1 % 5;
  }
  __syncthreads();

  const short8* lA8 = (const short8*)lsA;
  short* stp = enT + ((py0 + grp) * WD + pxx) * CH + c0;
  short4v sv;

#pragma unroll
  for (int c = 0; c < 4; ++c) {
    int base0 = c * 512 + col * 16;     // t = col
    int base1 = base0 + 256;            // t = col + 16
    short8 a[4];
    f32x4 acc0[4], acc1[4];
    // m-tile 0 (taps 0..15)
#pragma unroll
    for (int q = 0; q < 4; ++q) a[q] = lA8[base0 + (((q << 2) | grp) ^ (col & 7))];
#pragma unroll
    for (int s = 0; s < 4; ++s) {
      acc0[s] = (f32x4){0.f, 0.f, 0.f, 0.f};
#pragma unroll
      for (int q = 0; q < 4; ++q)
        acc0[s] = __builtin_amdgcn_mfma_f32_16x16x32_bf16(a[q], rv[s][q], acc0[s], 0, 0, 0);
    }
    // m-tile 1 (taps 16..31)
#pragma unroll
    for (int q = 0; q < 4; ++q) a[q] = lA8[base1 + (((q << 2) | grp) ^ (col & 7))];
#pragma unroll
    for (int s = 0; s < 4; ++s) {
      acc1[s] = (f32x4){0.f, 0.f, 0.f, 0.f};
#pragma unroll
      for (int q = 0; q < 4; ++q)
        acc1[s] = __builtin_amdgcn_mfma_f32_16x16x32_bf16(a[q], rv[s][q], acc1[s], 0, 0, 0);
    }
    // batched epilogue
    const float* fwc = fwv + c * 400;
    float part[4];
#pragma unroll
    for (int s = 0; s < 4; ++s) {
      float p = 0.f;
#pragma unroll
      for (int r = 0; r < 4; ++r) {
        p += fwc[idx0[r] + s * 20] * acc0[s][r];
        p += fwc[idx1[r] + s * 20] * acc1[s][r];
      }
      part[s] = p;
    }
#pragma unroll
    for (int s = 0; s < 4; ++s) part[s] += __shfl_xor(part[s], 16);
#pragma unroll
    for (int s = 0; s < 4; ++s) part[s] += __shfl_xor(part[s], 32);
    float val = (grp == 0) ? part[0] : (grp == 1) ? part[1]
              : (grp == 2) ? part[2] : part[3];
    sv[c] = f2bf(val);
  }
  *(short4v*)stp = sv;
}

// ---------------------------------------------------------------------------
// Kernel 4 (fused k_fuse + LN + k_out, all MFMA):
// ---------------------------------------------------------------------------
__global__ __launch_bounds__(256) void k_post(
    const short* __restrict__ enT_rgb, const short* __restrict__ enT_ev,
    const short* __restrict__ featT_rgb,
    const short* __restrict__ spwp, const short* __restrict__ outwp,
    const float* __restrict__ g, const float* __restrict__ b,
    float* __restrict__ out) {
  __shared__ short nlds[4][16 * 136];   // 17.4 KB
  __shared__ float sg[CH], sb[CH];
  int tid = threadIdx.x;
  if (tid < CH) { sg[tid] = g[tid]; sb[tid] = b[tid]; }
  __syncthreads();
  int wave = tid >> 6, lane = tid & 63, col = lane & 15, grp = lane >> 4;
  int p = blockIdx.x * 64 + wave * 16 + col;

  // gate GEMM: z[128 o][16 px] = sp_w @ en_ev
  const short8* bp = (const short8*)(enT_ev + p * CH);
  short8 bq[4];
#pragma unroll
  for (int q = 0; q < 4; ++q) bq[q] = bp[q * 4 + grp];
  const short8* ap = (const short8*)spwp;
  f32x4 z[8];
#pragma unroll
  for (int mt = 0; mt < 8; ++mt) {
    z[mt] = (f32x4){0.f, 0.f, 0.f, 0.f};
#pragma unroll
    for (int q = 0; q < 4; ++q)
      z[mt] = __builtin_amdgcn_mfma_f32_16x16x32_bf16(
          ap[(q * 128 + mt * 16 + col) * 4 + grp], bq[q], z[mt], 0, 0, 0);
  }

  // fused + LN stats
  const short4v* er = (const short4v*)(enT_rgb + p * CH);
  const short4v* fr = (const short4v*)(featT_rgb + p * CH);
  float fused[8][4];
  float s = 0.f, s2 = 0.f;
#pragma unroll
  for (int mt = 0; mt < 8; ++mt) {
    short4v e4 = er[mt * 4 + grp];
    short4v f4 = fr[mt * 4 + grp];
#pragma unroll
    for (int r = 0; r < 4; ++r) {
      float sig = 1.f / (1.f + __expf(-z[mt][r]));
      float f = bf2f(e4[r]) * (1.f + sig) + bf2f(f4[r]);
      fused[mt][r] = f; s += f; s2 += f * f;
    }
  }
  s += __shfl_xor(s, 16);  s += __shfl_xor(s, 32);
  s2 += __shfl_xor(s2, 16); s2 += __shfl_xor(s2, 32);
  float mean = s * (1.f / CH);
  float var = s2 * (1.f / CH) - mean * mean;
  float rinv = rsqrtf(var + EPSV);

  // normalize -> bf16 -> LDS [px][o] (stride 136)
  short* nl = &nlds[wave][0];
#pragma unroll
  for (int mt = 0; mt < 8; ++mt) {
    short4v nv;
#pragma unroll
    for (int r = 0; r < 4; ++r) {
      int o = mt * 16 + grp * 4 + r;
      nv[r] = f2bf((fused[mt][r] - mean) * rinv * sg[o] + sb[o]);
    }
    *(short4v*)(nl + col * 136 + mt * 16 + grp * 4) = nv;
  }

  // out GEMM: out[64 o][16 px] = out_w @ norm
  short8 nb[4];
#pragma unroll
  for (int q = 0; q < 4; ++q)
    nb[q] = *(const short8*)(nl + col * 136 + q * 32 + grp * 8);
  const short8* op = (const short8*)outwp;
#pragma unroll
  for (int mt = 0; mt < 4; ++mt) {
    f32x4 oacc = {0.f, 0.f, 0.f, 0.f};
#pragma unroll
    for (int q = 0; q < 4; ++q)
      oacc = __builtin_amdgcn_mfma_f32_16x16x32_bf16(
          op[(q * 64 + mt * 16 + col) * 4 + grp], nb[q], oacc, 0, 0, 0);
#pragma unroll
    for (int r = 0; r < 4; ++r)
      out[(mt * 16 + grp * 4 + r) * HW + p] = oacc[r];
  }
}

extern "C" void kernel_launch(void* const* d_in, const int* in_sizes, int n_in,
                              void* d_out, int out_size, void* d_ws, size_t ws_size,
                              hipStream_t stream) {
  const float* rgb  = (const float*)d_in[0];
  const float* ev   = (const float*)d_in[1];
  const float* cw   = (const float*)d_in[2];
  const float* g    = (const float*)d_in[3];
  const float* b    = (const float*)d_in[4];
  const float* w3   = (const float*)d_in[5];
  const float* df2  = (const float*)d_in[6];
  const float* spw  = (const float*)d_in[7];
  const float* outw = (const float*)d_in[8];
  float* out = (float*)d_out;
  char* wsb = (char*)d_ws;

  const size_t MB = 1u << 20;
  short* featT_rgb = (short*)(wsb);             // 4 MB
  short* featT_ev  = (short*)(wsb + 4 * MB);    // 4 MB
  short* rT_rgb    = (short*)(wsb + 8 * MB);    // 4 MB
  short* rT_ev     = (short*)(wsb + 12 * MB);   // 4 MB
  short* enT_rgb   = (short*)(wsb + 16 * MB);   // 4 MB
  short* enT_ev    = (short*)(wsb + 20 * MB);   // 4 MB
  short* xT_rgb    = (short*)(wsb + 24 * MB);   // 2 MB
  short* xT_ev     = (short*)(wsb + 26 * MB);   // 2 MB
  short* df2p      = (short*)(wsb + 28 * MB);   // 1 MB
  short* w3p       = (short*)(wsb + 29 * MB);   // 288 KB
  short* cwp       = (short*)(wsb + 30 * MB);   // 16 KB
  short* spwp      = (short*)(wsb + 31 * MB);   // 32 KB
  short* outwp     = (short*)(wsb + 32 * MB);   // 16 KB

  hipLaunchKernelGGL(k_prep_all, dim3(2880), dim3(256), 0, stream,
                     cw, w3, spw, outw, rgb, ev, df2,
                     cwp, w3p, spwp, outwp, xT_rgb, xT_ev, df2p);
  hipLaunchKernelGGL(k_feat_mfma, dim3(256, 1, 2), dim3(256), 0, stream,
                     xT_rgb, xT_ev, cwp, g, b, featT_rgb, featT_ev);
  hipLaunchKernelGGL(k_conv3_v3, dim3(256, 1, 2), dim3(256), 0, stream,
                     featT_rgb, featT_ev, w3p, rT_rgb, rT_ev);
  hipLaunchKernelGGL(k_filt_v6, dim3(64, 32, 2), dim3(256), 0, stream,
                     featT_rgb, featT_ev, rT_rgb, rT_ev, df2p, enT_rgb, enT_ev);
  hipLaunchKernelGGL(k_post, dim3(256), dim3(256), 0, stream,
                     enT_rgb, enT_ev, featT_rgb, spwp, outwp, g, b, out);
}